// Round 1
// baseline (7708.171 us; speedup 1.0000x reference)
//
#include <hip/hip_runtime.h>
#include <hip/hip_bf16.h>

// LSTM forward: T=512 (511 steps used), B=1024, I=128, H=256, gates=1024.
// Strategy: batch-partitioned persistent-per-wg recurrence, K=384 fused
// [x | h] GEMM vs precast bf16 W_cat, MFMA 16x16x32 bf16, fp32 state.

#define T_STEPS 511
#define BATCH   1024
#define IN      128
#define HID     256
#define NG      1024   // 4*HID
#define KTOT    384    // IN + HID
#define BWG     16     // batch rows per workgroup (MFMA M)

typedef __bf16 bf16x8 __attribute__((ext_vector_type(8)));
typedef float  f32x4  __attribute__((ext_vector_type(4)));

// LDS row strides in elements (+8 pad -> 16B-aligned rows, 2-way max bank alias)
#define XS 136   // 128 + 8
#define HS 264   // 256 + 8

__global__ void precast_kernel(const float* __restrict__ W_ih,
                               const float* __restrict__ W_hh,
                               const float* __restrict__ b_ih,
                               const float* __restrict__ b_hh,
                               __bf16* __restrict__ wcat,
                               float* __restrict__ bias) {
    int idx = blockIdx.x * blockDim.x + threadIdx.x;
    if (idx < NG * KTOT) {
        int n = idx / KTOT, k = idx % KTOT;
        float v = (k < IN) ? W_ih[n * IN + k] : W_hh[n * HID + (k - IN)];
        wcat[idx] = (__bf16)v;
    }
    if (idx < NG) bias[idx] = b_ih[idx] + b_hh[idx];
}

__device__ __forceinline__ float sigmoidf_fast(float v) {
    return 1.f / (1.f + __expf(-v));
}
__device__ __forceinline__ float tanhf_fast(float v) {
    // tanh(x) = 1 - 2/(1+e^{2x}); stable at +-inf
    return 1.f - 2.f / (1.f + __expf(2.f * v));
}

__global__ __launch_bounds__(512) void lstm_kernel(
    const float* __restrict__ x,      // (512, 1024, 128)
    const __bf16* __restrict__ wcat,  // (1024, 384) row-major bf16
    const float* __restrict__ bias,   // (1024,) = b_ih + b_hh
    const float* __restrict__ hx0,    // (256,)
    const float* __restrict__ cx0,    // (256,)
    float* __restrict__ out)          // h (1024,256) then c (1024,256)
{
    __shared__ alignas(16) __bf16 Ax[2][BWG * XS];  // x_t slice, double-buffered
    __shared__ alignas(16) __bf16 Ah[BWG * HS];     // h_t slice

    const int tid  = threadIdx.x;
    const int wave = tid >> 6;        // 0..7
    const int lane = tid & 63;
    const int col  = lane & 15;       // MFMA n / m index
    const int quad = lane >> 4;       // 0..3
    const int b0   = blockIdx.x * BWG;
    const int j0   = wave * 32;       // 32 hidden cols per wave (2 x 16)

    // ---- init h0 into LDS (16 rows x 256 cols broadcast of hx0) ----
    {
        int e = tid * 8;              // 512*8 = 4096 elements
        int m = e >> 8, j = e & 255;
        float4 v0 = *(const float4*)(hx0 + j);
        float4 v1 = *(const float4*)(hx0 + j + 4);
        __bf16* p = &Ah[m * HS + j];
        p[0] = (__bf16)v0.x; p[1] = (__bf16)v0.y;
        p[2] = (__bf16)v0.z; p[3] = (__bf16)v0.w;
        p[4] = (__bf16)v1.x; p[5] = (__bf16)v1.y;
        p[6] = (__bf16)v1.z; p[7] = (__bf16)v1.w;
    }
    // ---- load x_0 into buffer 0 ----
    const int m_x = tid >> 5;              // row 0..15
    const int k_x = (tid * 4) & 127;       // col, float4 granule
    {
        float4 v = *(const float4*)(x + (size_t)(b0 + m_x) * IN + k_x);
        __bf16* p = &Ax[0][m_x * XS + k_x];
        p[0] = (__bf16)v.x; p[1] = (__bf16)v.y;
        p[2] = (__bf16)v.z; p[3] = (__bf16)v.w;
    }

    // ---- per-lane bias for the 8 gate-column tiles this wave owns ----
    float bs[4][2];
    #pragma unroll
    for (int g = 0; g < 4; ++g)
        #pragma unroll
        for (int h2 = 0; h2 < 2; ++h2)
            bs[g][h2] = bias[g * 256 + j0 + h2 * 16 + col];

    // ---- W base pointers (quad offset folded in) ----
    const bf16x8* wb[4][2];
    #pragma unroll
    for (int g = 0; g < 4; ++g)
        #pragma unroll
        for (int h2 = 0; h2 < 2; ++h2) {
            int n = g * 256 + j0 + h2 * 16 + col;
            wb[g][h2] = (const bf16x8*)(wcat + (size_t)n * KTOT + quad * 8);
        }

    // ---- persistent cell state in registers ----
    float c[2][4], h[2][4];
    #pragma unroll
    for (int h2 = 0; h2 < 2; ++h2) {
        float cv = cx0[j0 + h2 * 16 + col];
        #pragma unroll
        for (int r = 0; r < 4; ++r) c[h2][r] = cv;
    }

    __syncthreads();

    for (int t = 0; t < T_STEPS; ++t) {
        // prefetch x_{t+1} (issued early, consumed after the mid-step barrier)
        float4 xp;
        bool do_pf = (t + 1 < T_STEPS);
        if (do_pf)
            xp = *(const float4*)(x + (size_t)(t + 1) * BATCH * IN
                                    + (size_t)(b0 + m_x) * IN + k_x);

        // A fragments: A[m = col][k = ks*32 + quad*8 + j]
        bf16x8 af[12];
        const __bf16* axb = &Ax[t & 1][0];
        #pragma unroll
        for (int ks = 0; ks < 4; ++ks)
            af[ks] = *(const bf16x8*)(axb + col * XS + ks * 32 + quad * 8);
        #pragma unroll
        for (int ks = 0; ks < 8; ++ks)
            af[4 + ks] = *(const bf16x8*)(&Ah[0] + col * HS + ks * 32 + quad * 8);

        // gates GEMM: 8 independent acc chains, W streamed from L2
        f32x4 acc[4][2];
        #pragma unroll
        for (int g = 0; g < 4; ++g)
            #pragma unroll
            for (int h2 = 0; h2 < 2; ++h2)
                acc[g][h2] = f32x4{0.f, 0.f, 0.f, 0.f};

        #pragma unroll
        for (int ks = 0; ks < 12; ++ks) {
            #pragma unroll
            for (int g = 0; g < 4; ++g) {
                #pragma unroll
                for (int h2 = 0; h2 < 2; ++h2) {
                    bf16x8 bfrag = wb[g][h2][ks * 4];  // + ks*32 elements
                    acc[g][h2] = __builtin_amdgcn_mfma_f32_16x16x32_bf16(
                        af[ks], bfrag, acc[g][h2], 0, 0, 0);
                }
            }
        }

        // elementwise LSTM cell (C-frag layout: row = quad*4+r, col = j0+h2*16+col)
        #pragma unroll
        for (int h2 = 0; h2 < 2; ++h2) {
            #pragma unroll
            for (int r = 0; r < 4; ++r) {
                float iv = acc[0][h2][r] + bs[0][h2];
                float fv = acc[1][h2][r] + bs[1][h2];
                float gv = acc[2][h2][r] + bs[2][h2];
                float ov = acc[3][h2][r] + bs[3][h2];
                float ig = sigmoidf_fast(iv);
                float fg = sigmoidf_fast(fv);
                float gt = tanhf_fast(gv);
                float og = sigmoidf_fast(ov);
                float cn = fg * c[h2][r] + ig * gt;
                c[h2][r] = cn;
                h[h2][r] = og * tanhf_fast(cn);
            }
        }

        __syncthreads();  // all waves done reading Ah / Ax[t&1]

        // write h_{t+1} into Ah (bf16)
        #pragma unroll
        for (int h2 = 0; h2 < 2; ++h2)
            #pragma unroll
            for (int r = 0; r < 4; ++r)
                Ah[(quad * 4 + r) * HS + j0 + h2 * 16 + col] = (__bf16)h[h2][r];

        // write x_{t+1} into the other buffer
        if (do_pf) {
            __bf16* p = &Ax[(t + 1) & 1][m_x * XS + k_x];
            p[0] = (__bf16)xp.x; p[1] = (__bf16)xp.y;
            p[2] = (__bf16)xp.z; p[3] = (__bf16)xp.w;
        }
        __syncthreads();
    }

    // final h, c (fp32 from registers)
    #pragma unroll
    for (int h2 = 0; h2 < 2; ++h2)
        #pragma unroll
        for (int r = 0; r < 4; ++r) {
            int row = b0 + quad * 4 + r;
            int jc  = j0 + h2 * 16 + col;
            out[(size_t)row * HID + jc] = h[h2][r];
            out[(size_t)BATCH * HID + (size_t)row * HID + jc] = c[h2][r];
        }
}

extern "C" void kernel_launch(void* const* d_in, const int* in_sizes, int n_in,
                              void* d_out, int out_size, void* d_ws, size_t ws_size,
                              hipStream_t stream) {
    const float* x    = (const float*)d_in[0];
    const float* W_ih = (const float*)d_in[1];
    const float* W_hh = (const float*)d_in[2];
    const float* b_ih = (const float*)d_in[3];
    const float* b_hh = (const float*)d_in[4];
    const float* hx0  = (const float*)d_in[5];
    const float* cx0  = (const float*)d_in[6];
    float* out = (float*)d_out;

    __bf16* wcat = (__bf16*)d_ws;
    float*  bias = (float*)((char*)d_ws + (size_t)NG * KTOT * sizeof(__bf16));

    precast_kernel<<<dim3((NG * KTOT + 255) / 256), dim3(256), 0, stream>>>(
        W_ih, W_hh, b_ih, b_hh, wcat, bias);
    lstm_kernel<<<dim3(BATCH / BWG), dim3(512), 0, stream>>>(
        x, wcat, bias, hx0, cx0, out);
}

// Round 2
// 5353.043 us; speedup vs baseline: 1.4400x; 1.4400x over previous
//
#include <hip/hip_runtime.h>
#include <hip/hip_bf16.h>

// LSTM forward: T=512 (511 steps), B=1024, I=128, H=256, 4H=1024.
// Round 2: register-persistent W. 256 wgs = (64 batch groups) x (4 hidden
// slices of 64 cols). Each wg holds its W slice (256 gate rows x 384 K, bf16)
// in VGPRs for the whole recurrence; per step the 4 partner wgs of a batch
// group exchange h-slices via global memory + device-scope counter.
// Cooperative launch guarantees co-residency (1 wg/CU x 256 CUs).

#define T_STEPS 511
#define BATCH   1024
#define IN      128
#define HID     256
#define NG      1024
#define KTOT    384
#define BWG     16
#define NGROUP  64
#define NSLICE  4

typedef __bf16 bf16x8 __attribute__((ext_vector_type(8)));
typedef float  f32x4  __attribute__((ext_vector_type(4)));

// LDS strides (elements), +8 pad
#define XS 136
#define HS 264

// workspace layout (bytes)
#define WCAT_OFF 0
#define BIAS_OFF 786432
#define HEXG_OFF 790528                    // 2*64*4*1024 floats = 2 MB
#define CNT_OFF  (790528 + 2097152)        // 64 groups * 16 ints

__global__ void precast_kernel(const float* __restrict__ W_ih,
                               const float* __restrict__ W_hh,
                               const float* __restrict__ b_ih,
                               const float* __restrict__ b_hh,
                               __bf16* __restrict__ wcat,
                               float* __restrict__ bias,
                               int* __restrict__ cnt) {
    int idx = blockIdx.x * blockDim.x + threadIdx.x;
    if (idx < NG * KTOT) {
        int n = idx / KTOT, k = idx % KTOT;
        float v = (k < IN) ? W_ih[n * IN + k] : W_hh[n * HID + (k - IN)];
        wcat[idx] = (__bf16)v;
    }
    if (idx < NG) bias[idx] = b_ih[idx] + b_hh[idx];
    if (idx < NGROUP * 16) cnt[idx] = 0;
}

__device__ __forceinline__ float sigmoidf_fast(float v) {
    return 1.f / (1.f + __expf(-v));
}
__device__ __forceinline__ float tanhf_fast(float v) {
    return 1.f - 2.f / (1.f + __expf(2.f * v));
}

__global__ __launch_bounds__(512, 2) void lstm_kernel(
    const float* __restrict__ x,      // (512,1024,128)
    const __bf16* __restrict__ wcat,  // (1024,384) bf16
    const float* __restrict__ bias,   // (1024,)
    const float* __restrict__ hx0,
    const float* __restrict__ cx0,
    float* __restrict__ hexg,         // (2,64,4,16,64) float
    int* __restrict__ cnt,            // (64,16) int
    float* __restrict__ out)          // h (1024,256), c (1024,256)
{
    __shared__ alignas(16) __bf16 Ax[2][BWG * XS];
    __shared__ alignas(16) __bf16 Ah[BWG * HS];

    const int tid  = threadIdx.x;
    const int bx   = blockIdx.x;
    // partner wgs of a group share (bx & 7) -> likely same XCD
    const int g    = (bx & 7) | ((bx >> 5) << 3);   // 0..63 batch group
    const int s    = (bx >> 3) & 3;                 // 0..3 hidden slice
    const int wave = tid >> 6;
    const int lane = tid & 63;
    const int col  = lane & 15;       // MFMA m / n lane index
    const int quad = lane >> 4;
    const int hf   = col >> 3;        // 0: {i,g} lane, 1: {f,o} lane
    const int b0   = g * BWG;
    const int j0   = s * 64;
    const int jw   = j0 + wave * 8;
    const int jcol = jw + (col & 7);  // this lane's hidden column

    int* cntg = cnt + g * 16;

    // ---- persistent W fragments: tile0 = {i|f}, tile1 = {g|o} ----
    const int n0 = (hf ? 256 : 0) + jcol;
    const int n1 = (hf ? 768 : 512) + jcol;
    bf16x8 wf0[12], wf1[12];
    #pragma unroll
    for (int ks = 0; ks < 12; ++ks) {
        wf0[ks] = *(const bf16x8*)(wcat + (size_t)n0 * KTOT + ks * 32 + quad * 8);
        wf1[ks] = *(const bf16x8*)(wcat + (size_t)n1 * KTOT + ks * 32 + quad * 8);
    }

    // ---- per-lane biases for hidden col jcol ----
    const float bi = bias[jcol];
    const float bfv = bias[256 + jcol];
    const float bg = bias[512 + jcol];
    const float bo = bias[768 + jcol];

    // ---- init h0 into LDS (16 rows x 256 cols of hx0) ----
    {
        int e = tid * 8;
        int m = e >> 8, j = e & 255;
        float4 v0 = *(const float4*)(hx0 + j);
        float4 v1 = *(const float4*)(hx0 + j + 4);
        __bf16* p = &Ah[m * HS + j];
        p[0] = (__bf16)v0.x; p[1] = (__bf16)v0.y;
        p[2] = (__bf16)v0.z; p[3] = (__bf16)v0.w;
        p[4] = (__bf16)v1.x; p[5] = (__bf16)v1.y;
        p[6] = (__bf16)v1.z; p[7] = (__bf16)v1.w;
    }
    // ---- x_0 into buffer 0 ----
    const int m_x = tid >> 5;
    const int k_x = (tid * 4) & 127;
    {
        float4 v = *(const float4*)(x + (size_t)(b0 + m_x) * IN + k_x);
        __bf16* p = &Ax[0][m_x * XS + k_x];
        p[0] = (__bf16)v.x; p[1] = (__bf16)v.y;
        p[2] = (__bf16)v.z; p[3] = (__bf16)v.w;
    }

    // ---- cell state (duplicated across lane pairs c / c+8) ----
    float cst[4], hn[4];
    {
        float cv = cx0[jcol];
        #pragma unroll
        for (int r = 0; r < 4; ++r) cst[r] = cv;
    }

    __syncthreads();

    for (int t = 0; t < T_STEPS; ++t) {
        const bool pf = (t + 1 < T_STEPS);
        float4 xp;
        if (pf)
            xp = *(const float4*)(x + (size_t)(t + 1) * BATCH * IN
                                    + (size_t)(b0 + m_x) * IN + k_x);

        // A fragments (shared by both gate tiles)
        bf16x8 af[12];
        const __bf16* axb = &Ax[t & 1][0];
        #pragma unroll
        for (int ks = 0; ks < 4; ++ks)
            af[ks] = *(const bf16x8*)(axb + col * XS + ks * 32 + quad * 8);
        #pragma unroll
        for (int ks = 0; ks < 8; ++ks)
            af[4 + ks] = *(const bf16x8*)(&Ah[0] + col * HS + ks * 32 + quad * 8);

        // 4 independent MFMA chains of 6 for ILP
        f32x4 aA0 = {0.f,0.f,0.f,0.f}, aA1 = {0.f,0.f,0.f,0.f};
        f32x4 aB0 = {0.f,0.f,0.f,0.f}, aB1 = {0.f,0.f,0.f,0.f};
        #pragma unroll
        for (int ks = 0; ks < 6; ++ks) {
            aA0 = __builtin_amdgcn_mfma_f32_16x16x32_bf16(af[ks], wf0[ks], aA0, 0, 0, 0);
            aB0 = __builtin_amdgcn_mfma_f32_16x16x32_bf16(af[ks], wf1[ks], aB0, 0, 0, 0);
        }
        #pragma unroll
        for (int ks = 6; ks < 12; ++ks) {
            aA1 = __builtin_amdgcn_mfma_f32_16x16x32_bf16(af[ks], wf0[ks], aA1, 0, 0, 0);
            aB1 = __builtin_amdgcn_mfma_f32_16x16x32_bf16(af[ks], wf1[ks], aB1, 0, 0, 0);
        }
        f32x4 accA = aA0 + aA1;   // i (hf=0) or f (hf=1) pre-act
        f32x4 accB = aB0 + aB1;   // g (hf=0) or o (hf=1) pre-act

        // pair i/f and g/o across lanes c <-> c+8, then elementwise
        #pragma unroll
        for (int r = 0; r < 4; ++r) {
            float oA = __shfl_xor(accA[r], 8, 64);
            float oB = __shfl_xor(accB[r], 8, 64);
            float iv = (hf ? oA : accA[r]) + bi;
            float fv = (hf ? accA[r] : oA) + bfv;
            float gv = (hf ? oB : accB[r]) + bg;
            float ov = (hf ? accB[r] : oB) + bo;
            float ig = sigmoidf_fast(iv);
            float fg = sigmoidf_fast(fv);
            float gt = tanhf_fast(gv);
            float og = sigmoidf_fast(ov);
            float cn = fg * cst[r] + ig * gt;
            cst[r] = cn;
            hn[r]  = og * tanhf_fast(cn);
        }

        __syncthreads();   // everyone done reading Ah / Ax[t&1]

        // own h slice -> LDS
        if (col < 8) {
            #pragma unroll
            for (int r = 0; r < 4; ++r)
                Ah[(quad * 4 + r) * HS + jcol] = (__bf16)hn[r];
        }

        if (t < T_STEPS - 1) {
            // own h slice -> exchange buffer (float)
            if (col < 8) {
                float* dst = hexg + ((((size_t)(t & 1) * NGROUP + g) * NSLICE + s) << 10)
                           + wave * 8 + col;
                #pragma unroll
                for (int r = 0; r < 4; ++r)
                    dst[(quad * 4 + r) * 64] = hn[r];
            }
            // next x tile -> other LDS buffer
            if (pf) {
                __bf16* p = &Ax[(t + 1) & 1][m_x * XS + k_x];
                p[0] = (__bf16)xp.x; p[1] = (__bf16)xp.y;
                p[2] = (__bf16)xp.z; p[3] = (__bf16)xp.w;
            }
            __syncthreads();   // vmcnt(0) drain: hexg stores complete

            if (tid == 0) {
                __hip_atomic_fetch_add(cntg, 1, __ATOMIC_RELEASE,
                                       __HIP_MEMORY_SCOPE_AGENT);
                const int target = 4 * (t + 1);
                int guard = 0;
                while (__hip_atomic_load(cntg, __ATOMIC_ACQUIRE,
                                         __HIP_MEMORY_SCOPE_AGENT) < target) {
                    if (++guard > (1 << 24)) break;   // fail-fast over deadlock
                }
            }
            __syncthreads();

            // pull the 3 partner slices into Ah
            const float* src = hexg + (((size_t)(t & 1) * NGROUP + g) * NSLICE << 10);
            #pragma unroll
            for (int ss = 0; ss < NSLICE; ++ss) {
                if (ss == s) continue;
                int idx = tid * 2;                 // 0..1022
                float2 v = *(const float2*)(src + (ss << 10) + idx);
                int row = idx >> 6, cc = idx & 63;
                __bf16* p = &Ah[row * HS + ss * 64 + cc];
                p[0] = (__bf16)v.x; p[1] = (__bf16)v.y;
            }
            __syncthreads();
        }
    }

    // final h, c — each wg owns its (16 batch x 64 hidden) block
    if (col < 8) {
        #pragma unroll
        for (int r = 0; r < 4; ++r) {
            int row = b0 + quad * 4 + r;
            out[(size_t)row * HID + jcol] = hn[r];
            out[(size_t)BATCH * HID + (size_t)row * HID + jcol] = cst[r];
        }
    }
}

extern "C" void kernel_launch(void* const* d_in, const int* in_sizes, int n_in,
                              void* d_out, int out_size, void* d_ws, size_t ws_size,
                              hipStream_t stream) {
    const float* x    = (const float*)d_in[0];
    const float* W_ih = (const float*)d_in[1];
    const float* W_hh = (const float*)d_in[2];
    const float* b_ih = (const float*)d_in[3];
    const float* b_hh = (const float*)d_in[4];
    const float* hx0  = (const float*)d_in[5];
    const float* cx0  = (const float*)d_in[6];
    float* outp = (float*)d_out;

    __bf16* wcat = (__bf16*)((char*)d_ws + WCAT_OFF);
    float*  bias = (float*)((char*)d_ws + BIAS_OFF);
    float*  hexg = (float*)((char*)d_ws + HEXG_OFF);
    int*    cnt  = (int*)((char*)d_ws + CNT_OFF);

    precast_kernel<<<dim3((NG * KTOT + 255) / 256), dim3(256), 0, stream>>>(
        W_ih, W_hh, b_ih, b_hh, wcat, bias, cnt);

    void* args[] = {(void*)&x, (void*)&wcat, (void*)&bias, (void*)&hx0,
                    (void*)&cx0, (void*)&hexg, (void*)&cnt, (void*)&outp};
    hipLaunchCooperativeKernel((const void*)lstm_kernel, dim3(256), dim3(512),
                               args, 0, stream);
}